// Round 19
// baseline (77.208 us; speedup 1.0000x reference)
//
#include <hip/hip_runtime.h>
#include <math.h>

// NeuroGameTransformer — 3-kernel pipeline (round-19).
// K1: cs = coal @ h via MFMA + Wv->WvT fold + m0 (r13-validated).
// K23: blocks 0..399 = k2 GEMM, M64 RE-TILE (was 200 x M128 = 0.78 blocks/CU;
//      now 400 blocks, per-wave acc 48->24 f32 — no spill headroom issues,
//      same swizzle/staging formulas, 2-deep prefetch kept, bit-identical
//      vsq); blocks 400..655 = k3a (r16-validated body).
// K3b: shapley.

typedef _Float16 h8 __attribute__((ext_vector_type(8)));
typedef float f4v __attribute__((ext_vector_type(4)));

constexpr int Bq = 256, Dq = 768, Nq = 128, Kq = 25;
// ws layout (bytes) — r13 layout
constexpr size_t WVT_OFF  = 0;                    // 768*768*2   = 1,179,648
constexpr size_t CS_OFF   = 1179648;              // 6400*768*2  = 9,830,400
constexpr size_t PART_OFF = 11010048;             // 4*6400*4    =   102,400
constexpr size_t M0_OFF   = 11112448;             // 256*128*4   =   131,072

// load one K-slice (24 strided scalars) into a float[24] register buffer
template <int KS>
__device__ __forceinline__ void ldb24(const float* __restrict__ hb2, float* arr) {
  #pragma unroll
  for (int ct = 0; ct < 3; ++ct) {
    const float* hp = hb2 + (size_t)(KS * 32) * 768 + ct * 16;
    #pragma unroll
    for (int j = 0; j < 8; ++j) arr[ct * 8 + j] = hp[(size_t)j * 768];
  }
}

__device__ __forceinline__ void stepk(const float* arr, const h8& a0, const h8& a1,
                                      f4v acc[2][3]) {
  #pragma unroll
  for (int ct = 0; ct < 3; ++ct) {
    h8 bfv;
    #pragma unroll
    for (int j = 0; j < 8; ++j) bfv[j] = (_Float16)arr[ct * 8 + j];
    acc[0][ct] = __builtin_amdgcn_mfma_f32_16x16x32_f16(a0, bfv, acc[0][ct], 0, 0, 0);
    acc[1][ct] = __builtin_amdgcn_mfma_f32_16x16x32_f16(a1, bfv, acc[1][ct], 0, 0, 0);
  }
}

// ---------------- K1: cs = coal @ h via MFMA + Wv transpose + m0 -------------
__global__ __launch_bounds__(256, 2) void k1_front(const float* __restrict__ hst,
                                                   const float* __restrict__ coal,
                                                   const float* __restrict__ Wv,
                                                   const float* __restrict__ Wp,
                                                   const float* __restrict__ bp,
                                                   _Float16* __restrict__ wvt,
                                                   _Float16* __restrict__ csf,
                                                   float* __restrict__ m0g) {
  __shared__ float tile[32 * 33];
  __shared__ float part2[256];
  const int t = threadIdx.x;
  const int b = blockIdx.x & 255;
  const int cc = blockIdx.x >> 8;
  const int l = t & 63, w = t >> 6;
  const int colbase = cc * 192;
  const int kb = (l >> 4) * 8;
  const float* hb = hst + (size_t)b * (128 * 768);

  if (blockIdx.x < 576) {
    const int bx = blockIdx.x % 24, by = blockIdx.x / 24;
    const int r = t >> 3, c4 = (t & 7) * 4;
    const float4 v = *reinterpret_cast<const float4*>(Wv + (size_t)(by * 32 + r) * 768 + bx * 32 + c4);
    tile[r * 33 + c4 + 0] = v.x; tile[r * 33 + c4 + 1] = v.y;
    tile[r * 33 + c4 + 2] = v.z; tile[r * 33 + c4 + 3] = v.w;
    __syncthreads();
    _Float16* dp = wvt + (size_t)(bx * 32 + r) * 768 + by * 32 + c4;
    dp[0] = (_Float16)tile[(c4 + 0) * 33 + r];
    dp[1] = (_Float16)tile[(c4 + 1) * 33 + r];
    dp[2] = (_Float16)tile[(c4 + 2) * 33 + r];
    dp[3] = (_Float16)tile[(c4 + 3) * 33 + r];
  }

  h8 afrag[2][4];
  #pragma unroll
  for (int Mt = 0; Mt < 2; ++Mt) {
    const int row = Mt * 16 + (l & 15);
    #pragma unroll
    for (int ks = 0; ks < 4; ++ks) {
      h8 v;
      if (row < 25) {
        const float4 p0 = *reinterpret_cast<const float4*>(coal + row * 128 + ks * 32 + kb);
        const float4 p1 = *reinterpret_cast<const float4*>(coal + row * 128 + ks * 32 + kb + 4);
        v[0] = (_Float16)p0.x; v[1] = (_Float16)p0.y;
        v[2] = (_Float16)p0.z; v[3] = (_Float16)p0.w;
        v[4] = (_Float16)p1.x; v[5] = (_Float16)p1.y;
        v[6] = (_Float16)p1.z; v[7] = (_Float16)p1.w;
      } else {
        #pragma unroll
        for (int j = 0; j < 8; ++j) v[j] = (_Float16)0.f;
      }
      afrag[Mt][ks] = v;
    }
  }

  f4v acc[2][3];
  #pragma unroll
  for (int Mt = 0; Mt < 2; ++Mt)
    #pragma unroll
    for (int ct = 0; ct < 3; ++ct) acc[Mt][ct] = (f4v){0.f, 0.f, 0.f, 0.f};

  const float* hb2 = hb + (size_t)kb * 768 + colbase + w * 48 + (l & 15);
  float ta[24], tb[24];
  ldb24<0>(hb2, ta);
  ldb24<1>(hb2, tb);
  stepk(ta, afrag[0][0], afrag[1][0], acc);
  ldb24<2>(hb2, ta);
  stepk(tb, afrag[0][1], afrag[1][1], acc);
  ldb24<3>(hb2, tb);
  stepk(ta, afrag[0][2], afrag[1][2], acc);
  stepk(tb, afrag[0][3], afrag[1][3], acc);

  #pragma unroll
  for (int Mt = 0; Mt < 2; ++Mt) {
    const int row0 = Mt * 16 + (l >> 4) * 4;
    #pragma unroll
    for (int ct = 0; ct < 3; ++ct) {
      const int col = colbase + (w * 3 + ct) * 16 + (l & 15);
      #pragma unroll
      for (int r = 0; r < 4; ++r) {
        const int rr = row0 + r;
        if (rr < 25)
          csf[((size_t)b * 25 + rr) * 768 + col] = (_Float16)acc[Mt][ct][r];
      }
    }
  }

  if (cc == 0) {
    const int j = t & 127, sg = t >> 7;
    float s = 0.f;
    for (int d = sg * 384; d < sg * 384 + 384; d += 4) {
      const float4 p4 = *reinterpret_cast<const float4*>(hb + d);
      s += p4.x * Wp[(d + 0) * 128 + j] + p4.y * Wp[(d + 1) * 128 + j]
         + p4.z * Wp[(d + 2) * 128 + j] + p4.w * Wp[(d + 3) * 128 + j];
    }
    part2[t] = s;
    __syncthreads();
    if (t < 128) {
      const float a0 = bp[t] + part2[t] + part2[t + 128];
      m0g[b * 128 + t] = tanhf(a0 * 0.1f);
    }
  }
}

// block-sum over waves 0..3 (other waves contribute zeros)
__device__ __forceinline__ float bsum4(float v, float* red) {
  #pragma unroll
  for (int o = 32; o > 0; o >>= 1) v += __shfl_down(v, o, 64);
  __syncthreads();
  if ((threadIdx.x & 63) == 0) red[threadIdx.x >> 6] = v;
  __syncthreads();
  return red[0] + red[1] + red[2] + red[3];
}

// ---------------- K23: blocks 0..399 = k2 GEMM (M64); 400..655 = k3a ---------
__global__ __launch_bounds__(512, 1) void k23(
    const _Float16* __restrict__ csA, const _Float16* __restrict__ wvtB,
    float* __restrict__ part,
    const float* __restrict__ Jg,   const float* __restrict__ lf,
    const float* __restrict__ m0g,
    const float* __restrict__ W1, const float* __restrict__ b1,
    const float* __restrict__ g1, const float* __restrict__ be1,
    const float* __restrict__ W2, const float* __restrict__ b2,
    const float* __restrict__ g2, const float* __restrict__ be2,
    const float* __restrict__ W3, const float* __restrict__ b3,
    float* __restrict__ out) {
  __shared__ __align__(16) char lds[(64 + 192) * 64];    // A 4096 B | B 12288 B
  __shared__ __align__(16) float m_sh[128];
  __shared__ float pmf[256];
  __shared__ __align__(16) float x1[256];
  __shared__ float x2[128];
  __shared__ float red[8];
  const int tid = threadIdx.x;

  if (blockIdx.x < 400) {
    // ===== k2 body, M64 tile (same formulas, rows/block 128 -> 64) ==========
    char* ldsA = lds;
    char* ldsB = lds + 4096;
    const int l = tid & 63, w = tid >> 6;
    const int rg = blockIdx.x >> 2, cc = blockIdx.x & 3;   // rg 0..99
    const size_t rowbase = (size_t)rg * 64;
    const int colbase = cc * 192;
    const int wm = w & 1, wn = w >> 1;

    const int fch = ((l >> 4) ^ (((l & 15) >> 1) & 3)) * 16;
    const int aoff = (l & 15) * 64 + fch;
    const int boff = (l & 15) * 64 + fch;

    const int srow = tid >> 2, sich = tid & 3;             // srow 0..127
    const int sch = sich ^ ((srow >> 1) & 3);
    // A staging: tid<256 covers rows 0..63
    const size_t gA_base = (rowbase + srow) * 768 + sich * 8;
    char* ldsA_w = ldsA + srow * 64 + sch * 16;
    // B staging: rows 0..127 by all, 128..191 by tid<256
    const size_t gB0_base = (size_t)(colbase + srow) * 768 + sich * 8;
    const size_t gB1_base = (size_t)(colbase + 128 + srow) * 768 + sich * 8;
    char* ldsB0_w = ldsB + srow * 64 + sch * 16;
    char* ldsB1_w = ldsB + (128 + srow) * 64 + sch * 16;

    f4v acc[2][3];
    #pragma unroll
    for (int mt = 0; mt < 2; ++mt)
      #pragma unroll
      for (int nt = 0; nt < 3; ++nt) acc[mt][nt] = (f4v){0.f, 0.f, 0.f, 0.f};

    // 2-deep register pipeline (r18-validated pattern)
    uint4 raA = {0, 0, 0, 0}, raB = {0, 0, 0, 0};
    if (tid < 256) {
      raA = *reinterpret_cast<const uint4*>(csA + gA_base);
      raB = *reinterpret_cast<const uint4*>(csA + gA_base + 32);
    }
    uint4 rb0A = *reinterpret_cast<const uint4*>(wvtB + gB0_base);
    uint4 rb0B = *reinterpret_cast<const uint4*>(wvtB + gB0_base + 32);
    uint4 rb1A = {0, 0, 0, 0}, rb1B = {0, 0, 0, 0};
    if (tid < 256) {
      rb1A = *reinterpret_cast<const uint4*>(wvtB + gB1_base);
      rb1B = *reinterpret_cast<const uint4*>(wvtB + gB1_base + 32);
    }

    for (int kp = 0; kp < 12; ++kp) {
      // even K-step: consume set A, refill for step 2kp+2
      if (tid < 256) *reinterpret_cast<uint4*>(ldsA_w) = raA;
      *reinterpret_cast<uint4*>(ldsB0_w) = rb0A;
      if (tid < 256) *reinterpret_cast<uint4*>(ldsB1_w) = rb1A;
      if (kp < 11) {
        if (tid < 256) raA = *reinterpret_cast<const uint4*>(csA + gA_base + (2 * kp + 2) * 32);
        rb0A = *reinterpret_cast<const uint4*>(wvtB + gB0_base + (2 * kp + 2) * 32);
        if (tid < 256) rb1A = *reinterpret_cast<const uint4*>(wvtB + gB1_base + (2 * kp + 2) * 32);
      }
      __syncthreads();
      {
        h8 af[2];
        #pragma unroll
        for (int mt = 0; mt < 2; ++mt)
          af[mt] = *reinterpret_cast<const h8*>(ldsA + (wm * 2 + mt) * 1024 + aoff);
        #pragma unroll
        for (int nt = 0; nt < 3; ++nt) {
          const h8 bf = *reinterpret_cast<const h8*>(ldsB + (wn * 3 + nt) * 1024 + boff);
          #pragma unroll
          for (int mt = 0; mt < 2; ++mt)
            acc[mt][nt] = __builtin_amdgcn_mfma_f32_16x16x32_f16(af[mt], bf, acc[mt][nt], 0, 0, 0);
        }
      }
      __syncthreads();
      // odd K-step: consume set B, refill for step 2kp+3
      if (tid < 256) *reinterpret_cast<uint4*>(ldsA_w) = raB;
      *reinterpret_cast<uint4*>(ldsB0_w) = rb0B;
      if (tid < 256) *reinterpret_cast<uint4*>(ldsB1_w) = rb1B;
      if (kp < 11) {
        if (tid < 256) raB = *reinterpret_cast<const uint4*>(csA + gA_base + (2 * kp + 3) * 32);
        rb0B = *reinterpret_cast<const uint4*>(wvtB + gB0_base + (2 * kp + 3) * 32);
        if (tid < 256) rb1B = *reinterpret_cast<const uint4*>(wvtB + gB1_base + (2 * kp + 3) * 32);
      }
      __syncthreads();
      {
        h8 af[2];
        #pragma unroll
        for (int mt = 0; mt < 2; ++mt)
          af[mt] = *reinterpret_cast<const h8*>(ldsA + (wm * 2 + mt) * 1024 + aoff);
        #pragma unroll
        for (int nt = 0; nt < 3; ++nt) {
          const h8 bf = *reinterpret_cast<const h8*>(ldsB + (wn * 3 + nt) * 1024 + boff);
          #pragma unroll
          for (int mt = 0; mt < 2; ++mt)
            acc[mt][nt] = __builtin_amdgcn_mfma_f32_16x16x32_f16(af[mt], bf, acc[mt][nt], 0, 0, 0);
        }
      }
      __syncthreads();
    }

    // epilogue: per-row sumsq; cross-wave reduce over the 4 wn-waves.
    float* redw = reinterpret_cast<float*>(lds);   // 64 rows x 4 wn = 1 KB
    #pragma unroll
    for (int mt = 0; mt < 2; ++mt) {
      #pragma unroll
      for (int r = 0; r < 4; ++r) {
        float s = acc[mt][0][r] * acc[mt][0][r] + acc[mt][1][r] * acc[mt][1][r]
                + acc[mt][2][r] * acc[mt][2][r];
        s += __shfl_xor(s, 1); s += __shfl_xor(s, 2);
        s += __shfl_xor(s, 4); s += __shfl_xor(s, 8);
        if ((l & 15) == 0) {
          const int row_local = (wm * 2 + mt) * 16 + (l >> 4) * 4 + r;
          redw[row_local * 4 + wn] = s;
        }
      }
    }
    __syncthreads();
    if (tid < 64) {
      const float tot = redw[tid * 4 + 0] + redw[tid * 4 + 1]
                      + redw[tid * 4 + 2] + redw[tid * 4 + 3];
      part[(size_t)cc * 6400 + rowbase + tid] = tot;
    }
  } else {
    // ================= k3a body (r16-validated, verbatim) ===================
    const int t = tid;
    const int b = blockIdx.x - 400;
    const int tn = t & 127, th = t >> 7;   // th 0..3; only th<2 used

    float Jreg[64];
    if (t < 256) {
      #pragma unroll
      for (int i = 0; i < 64; ++i)
        Jreg[i] = Jg[(size_t)(th * 64 + i) * 128 + tn];
    }

    float mloc = 0.f, lfv = 0.f, Jdg = 0.f;
    if (t < 128) {
      mloc = m0g[b * 128 + t];
      m_sh[t] = mloc;
      lfv = lf[t];
      Jdg = Jg[t * 128 + t];
    }
    __syncthreads();

    float hs = 0.f;
    for (int it = 0; it <= 25; ++it) {
      if (t < 256) {
        float ps0 = 0.f, ps1 = 0.f, ps2 = 0.f, ps3 = 0.f;
        #pragma unroll
        for (int q = 0; q < 16; ++q) {
          const float4 m4 = *reinterpret_cast<const float4*>(m_sh + th * 64 + q * 4);
          ps0 += Jreg[q * 4 + 0] * m4.x;
          ps1 += Jreg[q * 4 + 1] * m4.y;
          ps2 += Jreg[q * 4 + 2] * m4.z;
          ps3 += Jreg[q * 4 + 3] * m4.w;
        }
        pmf[t] = (ps0 + ps1) + (ps2 + ps3);
      }
      __syncthreads();
      if (it < 25) {
        if (t < 128) {
          const float h = lfv - mloc * Jdg + pmf[t] + pmf[t + 128];
          mloc = 0.7f * tanhf(h * 4.0f) + 0.3f * mloc;
          m_sh[t] = mloc;
        }
        __syncthreads();
      } else {
        if (t < 128) hs = lfv - mloc * Jdg + pmf[t] + pmf[t + 128];
      }
    }

    // free energy
    {
      const float a2 = (t < 128) ? fabsf(hs * 4.0f) : 0.f;
      const float fe = (t < 128) ? (a2 + log1pf(expf(-2.f * a2))) : 0.f;
      const float tot = bsum4(fe, red);
      if (t == 0) out[768 + b] = -0.25f * tot;
    }

    // MLP head
    float u = 0.f;
    if (t < 256) {
      u = b1[t];
      #pragma unroll 4
      for (int n = 0; n < 128; n += 4) {
        const float4 m4 = *reinterpret_cast<const float4*>(m_sh + n);
        u += m4.x * W1[(n + 0) * 256 + t] + m4.y * W1[(n + 1) * 256 + t]
           + m4.z * W1[(n + 2) * 256 + t] + m4.w * W1[(n + 3) * 256 + t];
      }
    }
    const float mean1 = bsum4(t < 256 ? u : 0.f, red) * (1.f / 256.f);
    const float xm1 = u - mean1;
    const float var1 = bsum4(t < 256 ? xm1 * xm1 : 0.f, red) * (1.f / 256.f);
    if (t < 256) {
      const float xln1 = xm1 * rsqrtf(var1 + 1e-5f) * g1[t] + be1[t];
      x1[t] = 0.5f * xln1 * (1.f + erff(xln1 * 0.70710678118654752f));
    }
    __syncthreads();

    float u2 = 0.f;
    if (t < 128) {
      u2 = b2[t];
      #pragma unroll 4
      for (int n = 0; n < 256; n += 4) {
        const float4 x4 = *reinterpret_cast<const float4*>(x1 + n);
        u2 += x4.x * W2[(n + 0) * 128 + t] + x4.y * W2[(n + 1) * 128 + t]
            + x4.z * W2[(n + 2) * 128 + t] + x4.w * W2[(n + 3) * 128 + t];
      }
    }
    const float mean2 = bsum4(t < 128 ? u2 : 0.f, red) * (1.f / 128.f);
    const float xm2 = u2 - mean2;
    const float var2 = bsum4(t < 128 ? xm2 * xm2 : 0.f, red) * (1.f / 128.f);
    if (t < 128) {
      const float xln2 = xm2 * rsqrtf(var2 + 1e-5f) * g2[t] + be2[t];
      x2[t] = 0.5f * xln2 * (1.f + erff(xln2 * 0.70710678118654752f));
    }
    __syncthreads();

    if (t < 3) {
      float lg = b3[t];
      #pragma unroll 4
      for (int n = 0; n < 128; ++n) lg += x2[n] * W3[n * 3 + t];
      out[b * 3 + t] = lg;
    }
  }
}

// ---------------- K3b: shapley (needs part from k2) --------------------------
__global__ __launch_bounds__(128, 1) void k3b(const float* __restrict__ part,
                                              const float* __restrict__ coal,
                                              const float* __restrict__ scale,
                                              float* __restrict__ out) {
  __shared__ float vsh[32];
  const int t = threadIdx.x, b = blockIdx.x;
  if (t < 25) {
    const float sq = part[b * 25 + t] + part[6400 + b * 25 + t]
                   + part[12800 + b * 25 + t] + part[19200 + b * 25 + t];
    vsh[t] = fmaxf(sqrtf(sq) * scale[0], 0.f);
  }
  __syncthreads();
  float sw = 0.f, c1 = 0.f, vs = 0.f;
  #pragma unroll
  for (int k = 0; k < 25; ++k) {
    const float c = coal[k * 128 + t];
    const float vk = vsh[k];
    sw += c * vk; vs += vk; c1 += c;
  }
  const float c0 = 25.f - c1;
  float shap = 0.f;
  if (c1 > 0.5f && c0 > 0.5f)
    shap = sw / fmaxf(c1, 1.f) - (vs - sw) / fmaxf(c0, 1.f);
  out[1024 + b * 128 + t] = shap;
}

// ---------------- launch ------------------------------------------------------
extern "C" void kernel_launch(void* const* d_in, const int* in_sizes, int n_in,
                              void* d_out, int out_size, void* d_ws, size_t ws_size,
                              hipStream_t stream) {
  const float* hst   = (const float*)d_in[0];
  const float* coal  = (const float*)d_in[1];
  const float* Wv    = (const float*)d_in[2];
  const float* scale = (const float*)d_in[3];
  const float* lf    = (const float*)d_in[4];
  const float* Jg    = (const float*)d_in[5];
  const float* Wp    = (const float*)d_in[6];
  const float* bp    = (const float*)d_in[7];
  const float* W1    = (const float*)d_in[8];
  const float* b1    = (const float*)d_in[9];
  const float* g1    = (const float*)d_in[10];
  const float* be1   = (const float*)d_in[11];
  const float* W2    = (const float*)d_in[12];
  const float* b2    = (const float*)d_in[13];
  const float* g2    = (const float*)d_in[14];
  const float* be2   = (const float*)d_in[15];
  const float* W3    = (const float*)d_in[16];
  const float* b3    = (const float*)d_in[17];
  float* out = (float*)d_out;

  char* ws = (char*)d_ws;  // needs >= 11,243,520 bytes
  _Float16* wvt = (_Float16*)(ws + WVT_OFF);
  _Float16* csf = (_Float16*)(ws + CS_OFF);
  float* part   = (float*)(ws + PART_OFF);
  float* m0g    = (float*)(ws + M0_OFF);

  hipLaunchKernelGGL(k1_front, dim3(1024), dim3(256), 0, stream,
                     hst, coal, Wv, Wp, bp, wvt, csf, m0g);
  hipLaunchKernelGGL(k23, dim3(656), dim3(512), 0, stream,
                     csf, wvt, part, Jg, lf, m0g,
                     W1, b1, g1, be1, W2, b2, g2, be2, W3, b3, out);
  hipLaunchKernelGGL(k3b, dim3(256), dim3(128), 0, stream,
                     part, coal, scale, out);
}

// Round 20
// 68.854 us; speedup vs baseline: 1.1213x; 1.1213x over previous
//
#include <hip/hip_runtime.h>
#include <math.h>

// NeuroGameTransformer — 3-kernel pipeline (round-20).
// K1: cs = coal @ h via MFMA + Wv->WvT fold + m0 (r13-validated).
// K23: blocks 0..199 = k2 GEMM M128xN192 (r18 tile — M64 reverted, it
//      regressed) with BK=64 double-panel staging: two K-panels per LDS
//      stage -> barrier pairs 24 -> 12, same 6-uint4 register set as r18,
//      bit-identical accumulation order. blocks 200..455 = k3a (r16 body).
// K3b: shapley.

typedef _Float16 h8 __attribute__((ext_vector_type(8)));
typedef float f4v __attribute__((ext_vector_type(4)));

constexpr int Bq = 256, Dq = 768, Nq = 128, Kq = 25;
// ws layout (bytes) — r13 layout
constexpr size_t WVT_OFF  = 0;                    // 768*768*2   = 1,179,648
constexpr size_t CS_OFF   = 1179648;              // 6400*768*2  = 9,830,400
constexpr size_t PART_OFF = 11010048;             // 4*6400*4    =   102,400
constexpr size_t M0_OFF   = 11112448;             // 256*128*4   =   131,072

// load one K-slice (24 strided scalars) into a float[24] register buffer
template <int KS>
__device__ __forceinline__ void ldb24(const float* __restrict__ hb2, float* arr) {
  #pragma unroll
  for (int ct = 0; ct < 3; ++ct) {
    const float* hp = hb2 + (size_t)(KS * 32) * 768 + ct * 16;
    #pragma unroll
    for (int j = 0; j < 8; ++j) arr[ct * 8 + j] = hp[(size_t)j * 768];
  }
}

__device__ __forceinline__ void stepk(const float* arr, const h8& a0, const h8& a1,
                                      f4v acc[2][3]) {
  #pragma unroll
  for (int ct = 0; ct < 3; ++ct) {
    h8 bfv;
    #pragma unroll
    for (int j = 0; j < 8; ++j) bfv[j] = (_Float16)arr[ct * 8 + j];
    acc[0][ct] = __builtin_amdgcn_mfma_f32_16x16x32_f16(a0, bfv, acc[0][ct], 0, 0, 0);
    acc[1][ct] = __builtin_amdgcn_mfma_f32_16x16x32_f16(a1, bfv, acc[1][ct], 0, 0, 0);
  }
}

// ---------------- K1: cs = coal @ h via MFMA + Wv transpose + m0 -------------
__global__ __launch_bounds__(256, 2) void k1_front(const float* __restrict__ hst,
                                                   const float* __restrict__ coal,
                                                   const float* __restrict__ Wv,
                                                   const float* __restrict__ Wp,
                                                   const float* __restrict__ bp,
                                                   _Float16* __restrict__ wvt,
                                                   _Float16* __restrict__ csf,
                                                   float* __restrict__ m0g) {
  __shared__ float tile[32 * 33];
  __shared__ float part2[256];
  const int t = threadIdx.x;
  const int b = blockIdx.x & 255;
  const int cc = blockIdx.x >> 8;
  const int l = t & 63, w = t >> 6;
  const int colbase = cc * 192;
  const int kb = (l >> 4) * 8;
  const float* hb = hst + (size_t)b * (128 * 768);

  if (blockIdx.x < 576) {
    const int bx = blockIdx.x % 24, by = blockIdx.x / 24;
    const int r = t >> 3, c4 = (t & 7) * 4;
    const float4 v = *reinterpret_cast<const float4*>(Wv + (size_t)(by * 32 + r) * 768 + bx * 32 + c4);
    tile[r * 33 + c4 + 0] = v.x; tile[r * 33 + c4 + 1] = v.y;
    tile[r * 33 + c4 + 2] = v.z; tile[r * 33 + c4 + 3] = v.w;
    __syncthreads();
    _Float16* dp = wvt + (size_t)(bx * 32 + r) * 768 + by * 32 + c4;
    dp[0] = (_Float16)tile[(c4 + 0) * 33 + r];
    dp[1] = (_Float16)tile[(c4 + 1) * 33 + r];
    dp[2] = (_Float16)tile[(c4 + 2) * 33 + r];
    dp[3] = (_Float16)tile[(c4 + 3) * 33 + r];
  }

  h8 afrag[2][4];
  #pragma unroll
  for (int Mt = 0; Mt < 2; ++Mt) {
    const int row = Mt * 16 + (l & 15);
    #pragma unroll
    for (int ks = 0; ks < 4; ++ks) {
      h8 v;
      if (row < 25) {
        const float4 p0 = *reinterpret_cast<const float4*>(coal + row * 128 + ks * 32 + kb);
        const float4 p1 = *reinterpret_cast<const float4*>(coal + row * 128 + ks * 32 + kb + 4);
        v[0] = (_Float16)p0.x; v[1] = (_Float16)p0.y;
        v[2] = (_Float16)p0.z; v[3] = (_Float16)p0.w;
        v[4] = (_Float16)p1.x; v[5] = (_Float16)p1.y;
        v[6] = (_Float16)p1.z; v[7] = (_Float16)p1.w;
      } else {
        #pragma unroll
        for (int j = 0; j < 8; ++j) v[j] = (_Float16)0.f;
      }
      afrag[Mt][ks] = v;
    }
  }

  f4v acc[2][3];
  #pragma unroll
  for (int Mt = 0; Mt < 2; ++Mt)
    #pragma unroll
    for (int ct = 0; ct < 3; ++ct) acc[Mt][ct] = (f4v){0.f, 0.f, 0.f, 0.f};

  const float* hb2 = hb + (size_t)kb * 768 + colbase + w * 48 + (l & 15);
  float ta[24], tb[24];
  ldb24<0>(hb2, ta);
  ldb24<1>(hb2, tb);
  stepk(ta, afrag[0][0], afrag[1][0], acc);
  ldb24<2>(hb2, ta);
  stepk(tb, afrag[0][1], afrag[1][1], acc);
  ldb24<3>(hb2, tb);
  stepk(ta, afrag[0][2], afrag[1][2], acc);
  stepk(tb, afrag[0][3], afrag[1][3], acc);

  #pragma unroll
  for (int Mt = 0; Mt < 2; ++Mt) {
    const int row0 = Mt * 16 + (l >> 4) * 4;
    #pragma unroll
    for (int ct = 0; ct < 3; ++ct) {
      const int col = colbase + (w * 3 + ct) * 16 + (l & 15);
      #pragma unroll
      for (int r = 0; r < 4; ++r) {
        const int rr = row0 + r;
        if (rr < 25)
          csf[((size_t)b * 25 + rr) * 768 + col] = (_Float16)acc[Mt][ct][r];
      }
    }
  }

  if (cc == 0) {
    const int j = t & 127, sg = t >> 7;
    float s = 0.f;
    for (int d = sg * 384; d < sg * 384 + 384; d += 4) {
      const float4 p4 = *reinterpret_cast<const float4*>(hb + d);
      s += p4.x * Wp[(d + 0) * 128 + j] + p4.y * Wp[(d + 1) * 128 + j]
         + p4.z * Wp[(d + 2) * 128 + j] + p4.w * Wp[(d + 3) * 128 + j];
    }
    part2[t] = s;
    __syncthreads();
    if (t < 128) {
      const float a0 = bp[t] + part2[t] + part2[t + 128];
      m0g[b * 128 + t] = tanhf(a0 * 0.1f);
    }
  }
}

// block-sum over waves 0..3 (other waves contribute zeros)
__device__ __forceinline__ float bsum4(float v, float* red) {
  #pragma unroll
  for (int o = 32; o > 0; o >>= 1) v += __shfl_down(v, o, 64);
  __syncthreads();
  if ((threadIdx.x & 63) == 0) red[threadIdx.x >> 6] = v;
  __syncthreads();
  return red[0] + red[1] + red[2] + red[3];
}

// ---------------- K23: blocks 0..199 = k2 GEMM (BK=64); 200..455 = k3a -------
__global__ __launch_bounds__(512, 1) void k23(
    const _Float16* __restrict__ csA, const _Float16* __restrict__ wvtB,
    float* __restrict__ part,
    const float* __restrict__ Jg,   const float* __restrict__ lf,
    const float* __restrict__ m0g,
    const float* __restrict__ W1, const float* __restrict__ b1,
    const float* __restrict__ g1, const float* __restrict__ be1,
    const float* __restrict__ W2, const float* __restrict__ b2,
    const float* __restrict__ g2, const float* __restrict__ be2,
    const float* __restrict__ W3, const float* __restrict__ b3,
    float* __restrict__ out) {
  __shared__ __align__(16) char lds[2 * (128 + 192) * 64];  // 2 panels, 40960 B
  __shared__ __align__(16) float m_sh[128];
  __shared__ float pmf[256];
  __shared__ __align__(16) float x1[256];
  __shared__ float x2[128];
  __shared__ float red[8];
  const int tid = threadIdx.x;

  if (blockIdx.x < 200) {
    // ===== k2 body: M128xN192 tile, BK=64 double-panel staging ==============
    char* ldsA0 = lds;
    char* ldsB0 = lds + 8192;
    char* ldsA1 = lds + 20480;
    char* ldsB1p = lds + 28672;
    const int l = tid & 63, w = tid >> 6;
    const int rg = blockIdx.x >> 2, cc = blockIdx.x & 3;
    const size_t rowbase = (size_t)rg * 128;
    const int colbase = cc * 192;
    const int wm = w & 1, wn = w >> 1;

    const int fch = ((l >> 4) ^ (((l & 15) >> 1) & 3)) * 16;
    const int aoff = (l & 15) * 64 + fch;
    const int boff = (l & 15) * 64 + fch;

    const int srow = tid >> 2, sich = tid & 3;
    const int sch = sich ^ ((srow >> 1) & 3);
    const size_t gA_base = (rowbase + srow) * 768 + sich * 8;
    const size_t gB0_base = (size_t)(colbase + srow) * 768 + sich * 8;
    const size_t gB1_base = (size_t)(colbase + 128 + srow) * 768 + sich * 8;
    const int wA = srow * 64 + sch * 16;
    const int wB0 = srow * 64 + sch * 16;
    const int wB1 = (128 + srow) * 64 + sch * 16;

    f4v acc[4][3];
    #pragma unroll
    for (int mt = 0; mt < 4; ++mt)
      #pragma unroll
      for (int nt = 0; nt < 3; ++nt) acc[mt][nt] = (f4v){0.f, 0.f, 0.f, 0.f};

    // stage set: 6 uint4 (two K-panels) — same register count as r18
    uint4 ra0 = *reinterpret_cast<const uint4*>(csA + gA_base);
    uint4 rb00 = *reinterpret_cast<const uint4*>(wvtB + gB0_base);
    uint4 rb10 = {0, 0, 0, 0};
    if (tid < 256) rb10 = *reinterpret_cast<const uint4*>(wvtB + gB1_base);
    uint4 ra1 = *reinterpret_cast<const uint4*>(csA + gA_base + 32);
    uint4 rb01 = *reinterpret_cast<const uint4*>(wvtB + gB0_base + 32);
    uint4 rb11 = {0, 0, 0, 0};
    if (tid < 256) rb11 = *reinterpret_cast<const uint4*>(wvtB + gB1_base + 32);

    for (int s = 0; s < 12; ++s) {
      // write both panels of stage s
      *reinterpret_cast<uint4*>(ldsA0 + wA) = ra0;
      *reinterpret_cast<uint4*>(ldsB0 + wB0) = rb00;
      if (tid < 256) *reinterpret_cast<uint4*>(ldsB0 + wB1) = rb10;
      *reinterpret_cast<uint4*>(ldsA1 + wA) = ra1;
      *reinterpret_cast<uint4*>(ldsB1p + wB0) = rb01;
      if (tid < 256) *reinterpret_cast<uint4*>(ldsB1p + wB1) = rb11;
      // prefetch stage s+1
      if (s < 11) {
        ra0 = *reinterpret_cast<const uint4*>(csA + gA_base + (2 * s + 2) * 32);
        rb00 = *reinterpret_cast<const uint4*>(wvtB + gB0_base + (2 * s + 2) * 32);
        if (tid < 256) rb10 = *reinterpret_cast<const uint4*>(wvtB + gB1_base + (2 * s + 2) * 32);
        ra1 = *reinterpret_cast<const uint4*>(csA + gA_base + (2 * s + 3) * 32);
        rb01 = *reinterpret_cast<const uint4*>(wvtB + gB0_base + (2 * s + 3) * 32);
        if (tid < 256) rb11 = *reinterpret_cast<const uint4*>(wvtB + gB1_base + (2 * s + 3) * 32);
      }
      __syncthreads();
      // panel 0 (K-step 2s)
      {
        h8 af[4];
        #pragma unroll
        for (int mt = 0; mt < 4; ++mt)
          af[mt] = *reinterpret_cast<const h8*>(ldsA0 + (wm * 4 + mt) * 1024 + aoff);
        #pragma unroll
        for (int nt = 0; nt < 3; ++nt) {
          const h8 bf = *reinterpret_cast<const h8*>(ldsB0 + (wn * 3 + nt) * 1024 + boff);
          #pragma unroll
          for (int mt = 0; mt < 4; ++mt)
            acc[mt][nt] = __builtin_amdgcn_mfma_f32_16x16x32_f16(af[mt], bf, acc[mt][nt], 0, 0, 0);
        }
      }
      // panel 1 (K-step 2s+1)
      {
        h8 af[4];
        #pragma unroll
        for (int mt = 0; mt < 4; ++mt)
          af[mt] = *reinterpret_cast<const h8*>(ldsA1 + (wm * 4 + mt) * 1024 + aoff);
        #pragma unroll
        for (int nt = 0; nt < 3; ++nt) {
          const h8 bf = *reinterpret_cast<const h8*>(ldsB1p + (wn * 3 + nt) * 1024 + boff);
          #pragma unroll
          for (int mt = 0; mt < 4; ++mt)
            acc[mt][nt] = __builtin_amdgcn_mfma_f32_16x16x32_f16(af[mt], bf, acc[mt][nt], 0, 0, 0);
        }
      }
      __syncthreads();
    }

    float* redw = reinterpret_cast<float*>(lds);
    #pragma unroll
    for (int mt = 0; mt < 4; ++mt) {
      #pragma unroll
      for (int r = 0; r < 4; ++r) {
        float s2 = acc[mt][0][r] * acc[mt][0][r] + acc[mt][1][r] * acc[mt][1][r]
                 + acc[mt][2][r] * acc[mt][2][r];
        s2 += __shfl_xor(s2, 1); s2 += __shfl_xor(s2, 2);
        s2 += __shfl_xor(s2, 4); s2 += __shfl_xor(s2, 8);
        if ((l & 15) == 0) {
          const int row_local = (wm * 4 + mt) * 16 + (l >> 4) * 4 + r;
          redw[row_local * 4 + wn] = s2;
        }
      }
    }
    __syncthreads();
    if (tid < 128) {
      const float tot = redw[tid * 4 + 0] + redw[tid * 4 + 1]
                      + redw[tid * 4 + 2] + redw[tid * 4 + 3];
      part[(size_t)cc * 6400 + rowbase + tid] = tot;
    }
  } else {
    // ================= k3a body (r16-validated, verbatim) ===================
    const int t = tid;
    const int b = blockIdx.x - 200;
    const int tn = t & 127, th = t >> 7;

    float Jreg[64];
    if (t < 256) {
      #pragma unroll
      for (int i = 0; i < 64; ++i)
        Jreg[i] = Jg[(size_t)(th * 64 + i) * 128 + tn];
    }

    float mloc = 0.f, lfv = 0.f, Jdg = 0.f;
    if (t < 128) {
      mloc = m0g[b * 128 + t];
      m_sh[t] = mloc;
      lfv = lf[t];
      Jdg = Jg[t * 128 + t];
    }
    __syncthreads();

    float hs = 0.f;
    for (int it = 0; it <= 25; ++it) {
      if (t < 256) {
        float ps0 = 0.f, ps1 = 0.f, ps2 = 0.f, ps3 = 0.f;
        #pragma unroll
        for (int q = 0; q < 16; ++q) {
          const float4 m4 = *reinterpret_cast<const float4*>(m_sh + th * 64 + q * 4);
          ps0 += Jreg[q * 4 + 0] * m4.x;
          ps1 += Jreg[q * 4 + 1] * m4.y;
          ps2 += Jreg[q * 4 + 2] * m4.z;
          ps3 += Jreg[q * 4 + 3] * m4.w;
        }
        pmf[t] = (ps0 + ps1) + (ps2 + ps3);
      }
      __syncthreads();
      if (it < 25) {
        if (t < 128) {
          const float h = lfv - mloc * Jdg + pmf[t] + pmf[t + 128];
          mloc = 0.7f * tanhf(h * 4.0f) + 0.3f * mloc;
          m_sh[t] = mloc;
        }
        __syncthreads();
      } else {
        if (t < 128) hs = lfv - mloc * Jdg + pmf[t] + pmf[t + 128];
      }
    }

    // free energy
    {
      const float a2 = (t < 128) ? fabsf(hs * 4.0f) : 0.f;
      const float fe = (t < 128) ? (a2 + log1pf(expf(-2.f * a2))) : 0.f;
      const float tot = bsum4(fe, red);
      if (t == 0) out[768 + b] = -0.25f * tot;
    }

    // MLP head
    float u = 0.f;
    if (t < 256) {
      u = b1[t];
      #pragma unroll 4
      for (int n = 0; n < 128; n += 4) {
        const float4 m4 = *reinterpret_cast<const float4*>(m_sh + n);
        u += m4.x * W1[(n + 0) * 256 + t] + m4.y * W1[(n + 1) * 256 + t]
           + m4.z * W1[(n + 2) * 256 + t] + m4.w * W1[(n + 3) * 256 + t];
      }
    }
    const float mean1 = bsum4(t < 256 ? u : 0.f, red) * (1.f / 256.f);
    const float xm1 = u - mean1;
    const float var1 = bsum4(t < 256 ? xm1 * xm1 : 0.f, red) * (1.f / 256.f);
    if (t < 256) {
      const float xln1 = xm1 * rsqrtf(var1 + 1e-5f) * g1[t] + be1[t];
      x1[t] = 0.5f * xln1 * (1.f + erff(xln1 * 0.70710678118654752f));
    }
    __syncthreads();

    float u2 = 0.f;
    if (t < 128) {
      u2 = b2[t];
      #pragma unroll 4
      for (int n = 0; n < 256; n += 4) {
        const float4 x4 = *reinterpret_cast<const float4*>(x1 + n);
        u2 += x4.x * W2[(n + 0) * 128 + t] + x4.y * W2[(n + 1) * 128 + t]
            + x4.z * W2[(n + 2) * 128 + t] + x4.w * W2[(n + 3) * 128 + t];
      }
    }
    const float mean2 = bsum4(t < 128 ? u2 : 0.f, red) * (1.f / 128.f);
    const float xm2 = u2 - mean2;
    const float var2 = bsum4(t < 128 ? xm2 * xm2 : 0.f, red) * (1.f / 128.f);
    if (t < 128) {
      const float xln2 = xm2 * rsqrtf(var2 + 1e-5f) * g2[t] + be2[t];
      x2[t] = 0.5f * xln2 * (1.f + erff(xln2 * 0.70710678118654752f));
    }
    __syncthreads();

    if (t < 3) {
      float lg = b3[t];
      #pragma unroll 4
      for (int n = 0; n < 128; ++n) lg += x2[n] * W3[n * 3 + t];
      out[b * 3 + t] = lg;
    }
  }
}

// ---------------- K3b: shapley (needs part from k2) --------------------------
__global__ __launch_bounds__(128, 1) void k3b(const float* __restrict__ part,
                                              const float* __restrict__ coal,
                                              const float* __restrict__ scale,
                                              float* __restrict__ out) {
  __shared__ float vsh[32];
  const int t = threadIdx.x, b = blockIdx.x;
  if (t < 25) {
    const float sq = part[b * 25 + t] + part[6400 + b * 25 + t]
                   + part[12800 + b * 25 + t] + part[19200 + b * 25 + t];
    vsh[t] = fmaxf(sqrtf(sq) * scale[0], 0.f);
  }
  __syncthreads();
  float sw = 0.f, c1 = 0.f, vs = 0.f;
  #pragma unroll
  for (int k = 0; k < 25; ++k) {
    const float c = coal[k * 128 + t];
    const float vk = vsh[k];
    sw += c * vk; vs += vk; c1 += c;
  }
  const float c0 = 25.f - c1;
  float shap = 0.f;
  if (c1 > 0.5f && c0 > 0.5f)
    shap = sw / fmaxf(c1, 1.f) - (vs - sw) / fmaxf(c0, 1.f);
  out[1024 + b * 128 + t] = shap;
}

// ---------------- launch ------------------------------------------------------
extern "C" void kernel_launch(void* const* d_in, const int* in_sizes, int n_in,
                              void* d_out, int out_size, void* d_ws, size_t ws_size,
                              hipStream_t stream) {
  const float* hst   = (const float*)d_in[0];
  const float* coal  = (const float*)d_in[1];
  const float* Wv    = (const float*)d_in[2];
  const float* scale = (const float*)d_in[3];
  const float* lf    = (const float*)d_in[4];
  const float* Jg    = (const float*)d_in[5];
  const float* Wp    = (const float*)d_in[6];
  const float* bp    = (const float*)d_in[7];
  const float* W1    = (const float*)d_in[8];
  const float* b1    = (const float*)d_in[9];
  const float* g1    = (const float*)d_in[10];
  const float* be1   = (const float*)d_in[11];
  const float* W2    = (const float*)d_in[12];
  const float* b2    = (const float*)d_in[13];
  const float* g2    = (const float*)d_in[14];
  const float* be2   = (const float*)d_in[15];
  const float* W3    = (const float*)d_in[16];
  const float* b3    = (const float*)d_in[17];
  float* out = (float*)d_out;

  char* ws = (char*)d_ws;  // needs >= 11,243,520 bytes
  _Float16* wvt = (_Float16*)(ws + WVT_OFF);
  _Float16* csf = (_Float16*)(ws + CS_OFF);
  float* part   = (float*)(ws + PART_OFF);
  float* m0g    = (float*)(ws + M0_OFF);

  hipLaunchKernelGGL(k1_front, dim3(1024), dim3(256), 0, stream,
                     hst, coal, Wv, Wp, bp, wvt, csf, m0g);
  hipLaunchKernelGGL(k23, dim3(456), dim3(512), 0, stream,
                     csf, wvt, part, Jg, lf, m0g,
                     W1, b1, g1, be1, W2, b2, g2, be2, W3, b3, out);
  hipLaunchKernelGGL(k3b, dim3(256), dim3(128), 0, stream,
                     part, coal, scale, out);
}